// Round 3
// baseline (940.966 us; speedup 1.0000x reference)
//
#include <hip/hip_runtime.h>
#include <math.h>

#define HP 265
#define NPIX 70225        // 265*265
#define ROWF 8480         // HP*32 floats per (b,h) row, channels-last
#define TWO_PI 6.28318530717958647692f

// ws layout (float offsets), channels-last x
#define OFF_X     0            // [8][265][265][32]            17,977,600
#define OFF_UPART 17977600     // [8][4][13][8480] cplx         7,055,360
#define OFF_G     25180416     // [8][32][24][12] cplx            147,456
#define OFF_A     25327872     // [8][265][32][12] cplx          1,628,160
#define OFF_TF    26956032     // [265][13][2]                      6,890

__device__ __forceinline__ float gelu_f(float v){
  return 0.5f * v * (1.0f + erff(v * 0.70710678118654752f));
}

// Forward twiddle table: Tf[h][k] = exp(-2*pi*i*(h*k mod 265)/265)
__global__ void k_init_tw(float* __restrict__ Tf){
  int idx = blockIdx.x*256 + threadIdx.x;
  if (idx >= HP*13) return;
  int h = idx / 13, k = idx % 13;
  int t = (h*k) % HP;
  float ang = -TWO_PI * (float)t / (float)HP;
  float s, c; sincosf(ang, &s, &c);
  Tf[idx*2+0] = c;
  Tf[idx*2+1] = s;
}

// fc0 (3->32, channels-last, zero pad) + copy x_en -> out sec3 + x_de -> out sec1
__global__ __launch_bounds__(256) void k_fc0(const float* __restrict__ xen,
                                             const float* __restrict__ w0,
                                             const float* __restrict__ b0,
                                             float* __restrict__ xb,
                                             float* __restrict__ out){
  int idx = blockIdx.x*256 + threadIdx.x;       // [b][h][w] over 265x265
  if (idx >= 8*NPIX) return;
  int w = idx % HP; int t = idx / HP; int h = t % HP; int b = t / HP;
  float o32[32];
  if (h < 256 && w < 256){
    const float* xp = xen + (((size_t)b*3)*256 + h)*256 + w;
    float c0 = xp[0], c1 = xp[65536], c2 = xp[131072];
    #pragma unroll
    for (int d = 0; d < 32; ++d)
      o32[d] = b0[d] + c0*w0[d] + c1*w0[32+d] + c2*w0[64+d];
    size_t be = ((size_t)b*3)*65536 + (h<<8) + w;
    out[1769472 + be]          = c0;
    out[1769472 + be + 65536]  = c1;
    out[1769472 + be + 131072] = c2;
    if (((h|w)&3) == 0){
      size_t db = ((size_t)b*3)*4096 + ((h>>2)<<6) + (w>>2);
      out[98304 + db]        = c0;
      out[98304 + db + 4096] = c1;
      out[98304 + db + 8192] = c2;
    }
  } else {
    #pragma unroll
    for (int d = 0; d < 32; ++d) o32[d] = 0.f;
  }
  float4* dst = (float4*)(xb + (size_t)idx*32);
  #pragma unroll
  for (int q = 0; q < 8; ++q)
    dst[q] = make_float4(o32[4*q], o32[4*q+1], o32[4*q+2], o32[4*q+3]);
}

// Row DFT over h, 13 modes, h split into 4 chunks (grid.y)
__global__ __launch_bounds__(256) void k_dft_h(const float* __restrict__ xb,
                                               const float* __restrict__ Tf,
                                               float2* __restrict__ Upart){
  int t  = blockIdx.x*256 + threadIdx.x;   // pix = w*32+i, 0..8479
  int hq = blockIdx.y;                     // 0..3
  int b  = blockIdx.z;                     // 0..7
  if (t >= ROWF) return;
  int h0 = hq*67;
  int h1 = (h0 + 67 < HP) ? h0 + 67 : HP;
  float ur[13], ui[13];
  #pragma unroll
  for (int k = 0; k < 13; ++k){ ur[k] = 0.f; ui[k] = 0.f; }
  const float* xp = xb + (size_t)(b*HP + h0)*ROWF + t;
  for (int h = h0; h < h1; ++h, xp += ROWF){
    float v = *xp;
    const float* tw = Tf + h*26;          // uniform -> scalar loads
    #pragma unroll
    for (int k = 0; k < 13; ++k){
      ur[k] = fmaf(v, tw[2*k+0], ur[k]);
      ui[k] = fmaf(v, tw[2*k+1], ui[k]);
    }
  }
  float2* up = Upart + ((size_t)(b*4 + hq))*13*ROWF + t;
  #pragma unroll
  for (int k = 0; k < 13; ++k)
    up[(size_t)k*ROWF] = make_float2(ur[k], ui[k]);
}

// Column DFT + mode mix, one block per (j, b).
// Phase 1: coalesced Upart read (lane over i), per-thread partial X over w-subset.
// Phase 2: LDS reduce over the 8 w-subsets -> X[b,i,j,kx] in LDS.
// Phase 3: G[b,o,j,kx] = sum_i X[b,i,j,kx] * (w1|w2)[l,i,o,ky,kx] (complex).
__global__ __launch_bounds__(256) void k_spec(const float2* __restrict__ Upart,
                                              const float* __restrict__ w1r,
                                              const float* __restrict__ w1i,
                                              const float* __restrict__ w2r,
                                              const float* __restrict__ w2i,
                                              float2* __restrict__ G, int l){
  __shared__ float part[256*25];   // per-thread 24 slots, padded to 25
  __shared__ float Xs[32*25];      // reduced X, padded
  int j = blockIdx.x;              // 0..23
  int b = blockIdx.y;              // 0..7
  int tid = threadIdx.x;
  int wsub = tid >> 5, i = tid & 31;
  int kk   = (j < 12) ? j : (24 - j);
  bool cj  = (j >= 12);
  float xr[12], xi[12];
  #pragma unroll
  for (int k = 0; k < 12; ++k){ xr[k] = 0.f; xi[k] = 0.f; }
  const float2* ub = Upart + ((size_t)(b*4*13 + kk))*ROWF;
  for (int w = wsub; w < HP; w += 8){
    const float2* p = ub + (size_t)w*32 + i;
    float2 u0 = p[0];
    float2 u1 = p[(size_t)13*ROWF];
    float2 u2 = p[(size_t)26*ROWF];
    float2 u3 = p[(size_t)39*ROWF];
    float ux = u0.x+u1.x+u2.x+u3.x;
    float uy = u0.y+u1.y+u2.y+u3.y;
    if (cj) uy = -uy;
    float bs, bc; sincosf(-TWO_PI*(float)w/(float)HP, &bs, &bc);
    float pr = 1.f, pi = 0.f;
    #pragma unroll
    for (int k = 0; k < 12; ++k){
      xr[k] = fmaf(ux, pr, fmaf(-uy, pi, xr[k]));
      xi[k] = fmaf(ux, pi, fmaf( uy, pr, xi[k]));
      float npr = pr*bc - pi*bs;
      pi = fmaf(pr, bs, pi*bc);
      pr = npr;
    }
  }
  #pragma unroll
  for (int k = 0; k < 12; ++k){
    part[tid*25 + 2*k]     = xr[k];
    part[tid*25 + 2*k + 1] = xi[k];
  }
  __syncthreads();
  {
    int sg = tid >> 5;             // 0..7 -> 3 slots each
    int ii = tid & 31;
    #pragma unroll
    for (int s0 = 0; s0 < 3; ++s0){
      int s = sg*3 + s0;
      float acc = 0.f;
      #pragma unroll
      for (int ws = 0; ws < 8; ++ws) acc += part[(ws*32 + ii)*25 + s];
      Xs[ii*25 + s] = acc;
    }
  }
  __syncthreads();
  int ky = (j < 12) ? j : (j - 12);
  const float* wr = (j < 12) ? w1r : w2r;
  const float* wi = (j < 12) ? w1i : w2i;
  for (int p = tid; p < 384; p += 256){
    int o = p / 12, kx = p % 12;
    size_t wbase = (size_t)l*147456 + (size_t)o*144 + (size_t)ky*12 + kx;
    float gr = 0.f, gi = 0.f;
    #pragma unroll 4
    for (int i2 = 0; i2 < 32; ++i2){
      float xvr = Xs[i2*25 + 2*kx];
      float xvi = Xs[i2*25 + 2*kx + 1];
      float a = wr[wbase + (size_t)i2*4608];
      float c = wi[wbase + (size_t)i2*4608];
      gr += xvr*a - xvi*c;
      gi += xvr*c + xvi*a;
    }
    G[((size_t)(b*32 + o)*24 + j)*12 + kx] = make_float2(gr, gi);
  }
}

// Inverse row synthesis: A[b,h,o,kx] = sum_j G[b,o,j,kx]*exp(+2pi i ky_j h/265)
__global__ __launch_bounds__(320) void k_idft_h(const float2* __restrict__ G,
                                                float* __restrict__ A){
  __shared__ float2 gs[288];
  int bo = blockIdx.x;     // b*32+o
  for (int i = threadIdx.x; i < 288; i += 320) gs[i] = G[(size_t)bo*288 + i];
  __syncthreads();
  int h = threadIdx.x;
  if (h >= HP) return;
  float ar[12], ai[12];
  #pragma unroll
  for (int k = 0; k < 12; ++k){ ar[k] = 0.f; ai[k] = 0.f; }
  for (int j = 0; j < 24; ++j){
    int ky = (j < 12) ? j : (241 + j);
    int t = (ky*h) % HP;
    float s, c; sincosf(TWO_PI*(float)t/(float)HP, &s, &c);
    #pragma unroll
    for (int k = 0; k < 12; ++k){
      float2 g = gs[j*12 + k];
      ar[k] = fmaf(g.x, c, fmaf(-g.y, s, ar[k]));
      ai[k] = fmaf(g.x, s, fmaf( g.y, c, ai[k]));
    }
  }
  int b = bo >> 5, o = bo & 31;
  float4* ap = (float4*)(A + (((size_t)(b*HP + h))*32 + o)*24);
  #pragma unroll
  for (int k = 0; k < 6; ++k)
    ap[k] = make_float4(ar[2*k], ai[2*k], ar[2*k+1], ai[2*k+1]);
}

// Final per-layer: x = irfft-synth(A)/N + pointwise(x) + bias; gelu unless last.
// A row + pw weights staged in LDS (block-uniform broadcast reads).
__global__ __launch_bounds__(320) void k_final(const float* __restrict__ A,
                                               const float* __restrict__ pw_w,
                                               const float* __restrict__ pw_b,
                                               float* __restrict__ xb, int l){
  __shared__ __align__(16) float As[768];
  __shared__ __align__(16) float pws[1056];
  int h = blockIdx.x;
  int b = blockIdx.y;
  const float* ag = A + (size_t)(b*HP + h)*768;
  for (int c = threadIdx.x; c < 768; c += 320) As[c] = ag[c];
  for (int c = threadIdx.x; c < 1056; c += 320)
    pws[c] = (c < 1024) ? pw_w[l*1024 + c] : pw_b[l*32 + (c - 1024)];
  __syncthreads();
  int w = threadIdx.x;
  if (w >= HP) return;
  float bs, bc; sincosf(TWO_PI*(float)w/(float)HP, &bs, &bc);
  float c2r[12], c2i[12];
  c2r[0] = 1.f; c2i[0] = 0.f;
  {
    float pr = 1.f, pi = 0.f;
    #pragma unroll
    for (int k = 1; k < 12; ++k){
      float npr = pr*bc - pi*bs;
      pi = fmaf(pr, bs, pi*bc);
      pr = npr;
      c2r[k] = 2.f*pr; c2i[k] = 2.f*pi;
    }
  }
  float xin[32];
  {
    const float4* xv = (const float4*)(xb + (size_t)(b*HP + h)*ROWF + (size_t)w*32);
    #pragma unroll
    for (int q = 0; q < 8; ++q){
      float4 v = xv[q];
      xin[4*q] = v.x; xin[4*q+1] = v.y; xin[4*q+2] = v.z; xin[4*q+3] = v.w;
    }
  }
  const float invN = 1.f/70225.f;
  float outv[32];
  #pragma unroll 4
  for (int o = 0; o < 32; ++o){
    const float* ao = As + o*24;
    float spec = ao[0];                             // Re(A0); Im of DC ignored
    #pragma unroll
    for (int k = 1; k < 12; ++k){
      spec = fmaf(ao[2*k],    c2r[k], spec);
      spec = fmaf(-ao[2*k+1], c2i[k], spec);
    }
    const float* pwo = pws + o*32;
    float p = pws[1024 + o];
    #pragma unroll
    for (int i = 0; i < 32; ++i) p = fmaf(xin[i], pwo[i], p);
    float val = fmaf(spec, invN, p);
    if (l < 3) val = gelu_f(val);
    outv[o] = val;
  }
  float4* dst = (float4*)(xb + (size_t)(b*HP + h)*ROWF + (size_t)w*32);
  #pragma unroll
  for (int q = 0; q < 8; ++q)
    dst[q] = make_float4(outv[4*q], outv[4*q+1], outv[4*q+2], outv[4*q+3]);
}

// Head: crop, fc1(32->128)+gelu, fc2(128->3), +x_en; weights in LDS
__global__ __launch_bounds__(256) void k_head(const float* __restrict__ xb,
                                              const float* __restrict__ xen,
                                              const float* __restrict__ fc1w,
                                              const float* __restrict__ fc1b,
                                              const float* __restrict__ fc2w,
                                              const float* __restrict__ fc2b,
                                              float* __restrict__ out){
  __shared__ __align__(16) float w1s[4096];
  __shared__ __align__(16) float f1b[128];
  __shared__ float f2s[384];
  __shared__ float f2b[3];
  int tid = threadIdx.x;
  for (int c = tid; c < 4096; c += 256) w1s[c] = fc1w[c];
  if (tid < 128) f1b[tid] = fc1b[tid];
  if (tid >= 128 && tid < 128+3) f2b[tid-128] = fc2b[tid-128];
  for (int c = tid; c < 384; c += 256) f2s[c] = fc2w[c];
  __syncthreads();
  int idx = blockIdx.x*256 + tid;            // b,h,w over 8*256*256
  int b = idx >> 16;
  int rem = idx & 65535;
  int h = rem >> 8, w = rem & 255;
  float xin[32];
  {
    const float4* xv = (const float4*)(xb + (size_t)(b*HP + h)*ROWF + (size_t)w*32);
    #pragma unroll
    for (int q = 0; q < 8; ++q){
      float4 v = xv[q];
      xin[4*q] = v.x; xin[4*q+1] = v.y; xin[4*q+2] = v.z; xin[4*q+3] = v.w;
    }
  }
  float a0 = f2b[0], a1 = f2b[1], a2 = f2b[2];
  for (int jg = 0; jg < 32; ++jg){
    float4 hv = *(const float4*)&f1b[jg*4];
    #pragma unroll
    for (int i = 0; i < 32; ++i){
      float4 wv = *(const float4*)&w1s[i*128 + jg*4];
      hv.x = fmaf(xin[i], wv.x, hv.x);
      hv.y = fmaf(xin[i], wv.y, hv.y);
      hv.z = fmaf(xin[i], wv.z, hv.z);
      hv.w = fmaf(xin[i], wv.w, hv.w);
    }
    hv.x = gelu_f(hv.x); hv.y = gelu_f(hv.y);
    hv.z = gelu_f(hv.z); hv.w = gelu_f(hv.w);
    const float* f2p = f2s + jg*12;
    a0 = fmaf(hv.x, f2p[0], a0); a1 = fmaf(hv.x, f2p[1],  a1); a2 = fmaf(hv.x, f2p[2],  a2);
    a0 = fmaf(hv.y, f2p[3], a0); a1 = fmaf(hv.y, f2p[4],  a1); a2 = fmaf(hv.y, f2p[5],  a2);
    a0 = fmaf(hv.z, f2p[6], a0); a1 = fmaf(hv.z, f2p[7],  a1); a2 = fmaf(hv.z, f2p[8],  a2);
    a0 = fmaf(hv.w, f2p[9], a0); a1 = fmaf(hv.w, f2p[10], a1); a2 = fmaf(hv.w, f2p[11], a2);
  }
  int pix = (h << 8) | w;
  size_t be = ((size_t)b*3)*65536 + pix;
  float p0 = a0 + xen[be];
  float p1 = a1 + xen[be + 65536];
  float p2 = a2 + xen[be + 131072];
  out[196608 + be]          = p0;
  out[196608 + be + 65536]  = p1;
  out[196608 + be + 131072] = p2;
  if (((h|w)&3) == 0){
    size_t db = ((size_t)b*3)*4096 + ((h>>2)<<6) + (w>>2);
    out[db]        = p0;
    out[db + 4096] = p1;
    out[db + 8192] = p2;
  }
}

extern "C" void kernel_launch(void* const* d_in, const int* in_sizes, int n_in,
                              void* d_out, int out_size, void* d_ws, size_t ws_size,
                              hipStream_t stream){
  const float* x_en  = (const float*)d_in[0];
  const float* fc0_w = (const float*)d_in[2];
  const float* fc0_b = (const float*)d_in[3];
  const float* w1r   = (const float*)d_in[4];
  const float* w1i   = (const float*)d_in[5];
  const float* w2r   = (const float*)d_in[6];
  const float* w2i   = (const float*)d_in[7];
  const float* pw_w  = (const float*)d_in[8];
  const float* pw_b  = (const float*)d_in[9];
  const float* fc1_w = (const float*)d_in[10];
  const float* fc1_b = (const float*)d_in[11];
  const float* fc2_w = (const float*)d_in[12];
  const float* fc2_b = (const float*)d_in[13];
  float* out = (float*)d_out;
  float* ws  = (float*)d_ws;

  float*  xb    = ws + OFF_X;
  float2* Upart = (float2*)(ws + OFF_UPART);
  float2* G     = (float2*)(ws + OFF_G);
  float*  A     = ws + OFF_A;
  float*  Tf    = ws + OFF_TF;

  k_init_tw<<<14, 256, 0, stream>>>(Tf);
  k_fc0<<<2195, 256, 0, stream>>>(x_en, fc0_w, fc0_b, xb, out);
  for (int l = 0; l < 4; ++l){
    k_dft_h<<<dim3(34,4,8), 256, 0, stream>>>(xb, Tf, Upart);
    k_spec<<<dim3(24,8), 256, 0, stream>>>(Upart, w1r, w1i, w2r, w2i, G, l);
    k_idft_h<<<256, 320, 0, stream>>>(G, A);
    k_final<<<dim3(265,8), 320, 0, stream>>>(A, pw_w, pw_b, xb, l);
  }
  k_head<<<2048, 256, 0, stream>>>(xb, x_en, fc1_w, fc1_b, fc2_w, fc2_b, out);
}

// Round 4
// 426.630 us; speedup vs baseline: 2.2056x; 2.2056x over previous
//
#include <hip/hip_runtime.h>
#include <math.h>

#define HP 265
#define NPIX 70225        // 265*265
#define ROWF 8480         // HP*32 elements per (b,h) row, channels-last
#define TWO_PI 6.28318530717958647692f

// ws layout (float offsets); xb is bf16 (ushort)
#define OFF_X     0            // [8][265][265][32] ushort  = 8,988,800 f32-slots
#define OFF_UPART 8988800      // [8][4][13][8480] cplx f32 = 7,055,360
#define OFF_G     16044160     // [8][32][24][12] cplx f32  =   147,456
#define OFF_A     16191616     // [8][265][32][24] f32      = 1,628,160
#define OFF_TF    17819776     // [265][13][2] f32          =     6,890
#define OFF_TS    17826668     // [272][32] ushort          =     4,352 f32-slots

typedef __attribute__((ext_vector_type(8))) short short8;
typedef __attribute__((ext_vector_type(4))) float f32x4;

__device__ __forceinline__ float gelu_f(float v){
  return 0.5f * v * (1.0f + erff(v * 0.70710678118654752f));
}
__device__ __forceinline__ unsigned short f2b(float f){
  unsigned u = __float_as_uint(f);
  u += 0x7FFFu + ((u >> 16) & 1u);
  return (unsigned short)(u >> 16);
}
__device__ __forceinline__ float b2f(unsigned short s){
  return __uint_as_float(((unsigned)s) << 16);
}
__device__ __forceinline__ unsigned pk(unsigned short lo, unsigned short hi){
  return (unsigned)lo | ((unsigned)hi << 16);
}

// Tf[h][k] = exp(-2pi i h k/265) f32; Tsyn[w][kap<24] = inverse-synth bf16 (invN folded)
__global__ void k_init(float* __restrict__ Tf, unsigned short* __restrict__ Ts){
  int idx = blockIdx.x*256 + threadIdx.x;
  if (idx < HP*13){
    int h = idx/13, k = idx%13;
    int t = (h*k) % HP;
    float s, c; sincosf(-TWO_PI*(float)t/(float)HP, &s, &c);
    Tf[2*idx] = c; Tf[2*idx+1] = s;
  }
  if (idx < 272*32){
    int w = idx >> 5, kap = idx & 31;
    unsigned short v = 0;
    if (w < HP && kap < 24){
      int k = kap >> 1;
      int t = (w*k) % HP;
      float s, c; sincosf(TWO_PI*(float)t/(float)HP, &s, &c);
      const float invN = 1.f/70225.f;
      float val = (!(kap&1)) ? invN*(k==0 ? 1.f : 2.f*c)
                             : ((k==0) ? 0.f : -invN*2.f*s);
      v = f2b(val);
    }
    Ts[idx] = v;
  }
}

// fc0 (3->32, bf16 channels-last, zero pad) + copy x_en/x_de to out
__global__ __launch_bounds__(256) void k_fc0(const float* __restrict__ xen,
                                             const float* __restrict__ w0,
                                             const float* __restrict__ b0,
                                             unsigned short* __restrict__ xb,
                                             float* __restrict__ out){
  int idx = blockIdx.x*256 + threadIdx.x;
  if (idx >= 8*NPIX) return;
  int w = idx % HP; int t = idx / HP; int h = t % HP; int b = t / HP;
  unsigned short o16[32];
  if (h < 256 && w < 256){
    const float* xp = xen + (((size_t)b*3)*256 + h)*256 + w;
    float c0 = xp[0], c1 = xp[65536], c2 = xp[131072];
    #pragma unroll
    for (int d = 0; d < 32; ++d)
      o16[d] = f2b(b0[d] + c0*w0[d] + c1*w0[32+d] + c2*w0[64+d]);
    size_t be = ((size_t)b*3)*65536 + (h<<8) + w;
    out[1769472 + be]          = c0;
    out[1769472 + be + 65536]  = c1;
    out[1769472 + be + 131072] = c2;
    if (((h|w)&3) == 0){
      size_t db = ((size_t)b*3)*4096 + ((h>>2)<<6) + (w>>2);
      out[98304 + db]        = c0;
      out[98304 + db + 4096] = c1;
      out[98304 + db + 8192] = c2;
    }
  } else {
    #pragma unroll
    for (int d = 0; d < 32; ++d) o16[d] = 0;
  }
  uint4* dst = (uint4*)(xb + (size_t)idx*32);
  #pragma unroll
  for (int q = 0; q < 4; ++q)
    dst[q] = make_uint4(pk(o16[8*q],o16[8*q+1]), pk(o16[8*q+2],o16[8*q+3]),
                        pk(o16[8*q+4],o16[8*q+5]), pk(o16[8*q+6],o16[8*q+7]));
}

// Row DFT over h, 13 modes, bf16 input, 2 elements/thread
__global__ __launch_bounds__(256) void k_dft_h(const unsigned short* __restrict__ xb,
                                               const float* __restrict__ Tf,
                                               float2* __restrict__ Upart){
  int t2 = blockIdx.x*256 + threadIdx.x;   // 0..4239
  if (t2 >= 4240) return;
  int hq = blockIdx.y, b = blockIdx.z;
  int h0 = hq*67;
  int h1 = (h0 + 67 < HP) ? h0 + 67 : HP;
  float ur0[13], ui0[13], ur1[13], ui1[13];
  #pragma unroll
  for (int k = 0; k < 13; ++k){ ur0[k]=0.f; ui0[k]=0.f; ur1[k]=0.f; ui1[k]=0.f; }
  const unsigned short* xp = xb + (size_t)(b*HP + h0)*ROWF + 2*t2;
  for (int h = h0; h < h1; ++h, xp += ROWF){
    unsigned u = *(const unsigned*)xp;
    float v0 = b2f((unsigned short)(u & 0xFFFF));
    float v1 = b2f((unsigned short)(u >> 16));
    const float* tw = Tf + h*26;          // uniform -> scalar loads
    #pragma unroll
    for (int k = 0; k < 13; ++k){
      float cr = tw[2*k], ci = tw[2*k+1];
      ur0[k] = fmaf(v0, cr, ur0[k]); ui0[k] = fmaf(v0, ci, ui0[k]);
      ur1[k] = fmaf(v1, cr, ur1[k]); ui1[k] = fmaf(v1, ci, ui1[k]);
    }
  }
  float* up = (float*)(Upart + ((size_t)(b*4 + hq))*13*ROWF + 2*t2);
  #pragma unroll
  for (int k = 0; k < 13; ++k)
    *(float4*)(up + (size_t)k*ROWF*2) = make_float4(ur0[k], ui0[k], ur1[k], ui1[k]);
}

// Column DFT + mode mix, one block per (j, b). (unchanged from R3)
__global__ __launch_bounds__(256) void k_spec(const float2* __restrict__ Upart,
                                              const float* __restrict__ w1r,
                                              const float* __restrict__ w1i,
                                              const float* __restrict__ w2r,
                                              const float* __restrict__ w2i,
                                              float2* __restrict__ G, int l){
  __shared__ float part[256*25];
  __shared__ float Xs[32*25];
  int j = blockIdx.x;
  int b = blockIdx.y;
  int tid = threadIdx.x;
  int wsub = tid >> 5, i = tid & 31;
  int kk   = (j < 12) ? j : (24 - j);
  bool cj  = (j >= 12);
  float xr[12], xi[12];
  #pragma unroll
  for (int k = 0; k < 12; ++k){ xr[k] = 0.f; xi[k] = 0.f; }
  const float2* ub = Upart + ((size_t)(b*4*13 + kk))*ROWF;
  for (int w = wsub; w < HP; w += 8){
    const float2* p = ub + (size_t)w*32 + i;
    float2 u0 = p[0];
    float2 u1 = p[(size_t)13*ROWF];
    float2 u2 = p[(size_t)26*ROWF];
    float2 u3 = p[(size_t)39*ROWF];
    float ux = u0.x+u1.x+u2.x+u3.x;
    float uy = u0.y+u1.y+u2.y+u3.y;
    if (cj) uy = -uy;
    float bs, bc; sincosf(-TWO_PI*(float)w/(float)HP, &bs, &bc);
    float pr = 1.f, pi = 0.f;
    #pragma unroll
    for (int k = 0; k < 12; ++k){
      xr[k] = fmaf(ux, pr, fmaf(-uy, pi, xr[k]));
      xi[k] = fmaf(ux, pi, fmaf( uy, pr, xi[k]));
      float npr = pr*bc - pi*bs;
      pi = fmaf(pr, bs, pi*bc);
      pr = npr;
    }
  }
  #pragma unroll
  for (int k = 0; k < 12; ++k){
    part[tid*25 + 2*k]     = xr[k];
    part[tid*25 + 2*k + 1] = xi[k];
  }
  __syncthreads();
  {
    int sg = tid >> 5;
    int ii = tid & 31;
    #pragma unroll
    for (int s0 = 0; s0 < 3; ++s0){
      int s = sg*3 + s0;
      float acc = 0.f;
      #pragma unroll
      for (int ws = 0; ws < 8; ++ws) acc += part[(ws*32 + ii)*25 + s];
      Xs[ii*25 + s] = acc;
    }
  }
  __syncthreads();
  int ky = (j < 12) ? j : (j - 12);
  const float* wr = (j < 12) ? w1r : w2r;
  const float* wi = (j < 12) ? w1i : w2i;
  for (int p = tid; p < 384; p += 256){
    int o = p / 12, kx = p % 12;
    size_t wbase = (size_t)l*147456 + (size_t)o*144 + (size_t)ky*12 + kx;
    float gr = 0.f, gi = 0.f;
    #pragma unroll 4
    for (int i2 = 0; i2 < 32; ++i2){
      float xvr = Xs[i2*25 + 2*kx];
      float xvi = Xs[i2*25 + 2*kx + 1];
      float a = wr[wbase + (size_t)i2*4608];
      float c = wi[wbase + (size_t)i2*4608];
      gr += xvr*a - xvi*c;
      gi += xvr*c + xvi*a;
    }
    G[((size_t)(b*32 + o)*24 + j)*12 + kx] = make_float2(gr, gi);
  }
}

// Inverse row synthesis (unchanged): A[b,h][o][2k]=Re, [2k+1]=Im
__global__ __launch_bounds__(320) void k_idft_h(const float2* __restrict__ G,
                                                float* __restrict__ A){
  __shared__ float2 gs[288];
  int bo = blockIdx.x;
  for (int i = threadIdx.x; i < 288; i += 320) gs[i] = G[(size_t)bo*288 + i];
  __syncthreads();
  int h = threadIdx.x;
  if (h >= HP) return;
  float ar[12], ai[12];
  #pragma unroll
  for (int k = 0; k < 12; ++k){ ar[k] = 0.f; ai[k] = 0.f; }
  for (int j = 0; j < 24; ++j){
    int ky = (j < 12) ? j : (241 + j);
    int t = (ky*h) % HP;
    float s, c; sincosf(TWO_PI*(float)t/(float)HP, &s, &c);
    #pragma unroll
    for (int k = 0; k < 12; ++k){
      float2 g = gs[j*12 + k];
      ar[k] = fmaf(g.x, c, fmaf(-g.y, s, ar[k]));
      ai[k] = fmaf(g.x, s, fmaf( g.y, c, ai[k]));
    }
  }
  int b = bo >> 5, o = bo & 31;
  float4* ap = (float4*)(A + (((size_t)(b*HP + h))*32 + o)*24);
  #pragma unroll
  for (int k = 0; k < 6; ++k)
    ap[k] = make_float4(ar[2*k], ai[2*k], ar[2*k+1], ai[2*k+1]);
}

// MFMA final: C[w][o] = Tsyn[w][:24]@A + x[w][:]@pw^T + bias; gelu (l<3); in-place bf16 x
__global__ __launch_bounds__(256) void k_final(const float* __restrict__ A,
                                               const unsigned short* __restrict__ Tsyn,
                                               const float* __restrict__ pw_w,
                                               const float* __restrict__ pw_b,
                                               unsigned short* __restrict__ xb, int l){
  __shared__ unsigned short btA[32*40];
  __shared__ unsigned short btP[32*40];
  __shared__ float pwbs[32];
  __shared__ float buf[4][16*36];
  int tid = threadIdx.x;
  int h = blockIdx.x, b = blockIdx.y;
  const float* Ag = A + (size_t)(b*HP + h)*768;
  for (int i = tid; i < 768; i += 256){
    int o = i/24, k = i - o*24;
    btA[o*40 + k] = f2b(Ag[i]);
  }
  { int o = tid >> 3, c = 24 + (tid & 7); btA[o*40 + c] = 0; }
  for (int i = tid; i < 1024; i += 256)
    btP[(i>>5)*40 + (i&31)] = f2b(pw_w[l*1024 + i]);
  if (tid < 32) pwbs[tid] = pw_b[l*32 + tid];
  __syncthreads();
  int wid = tid>>6, lane = tid&63, lr = lane&15, g = lane>>4, lk = g*8;
  short8 bA0 = *(const short8*)&btA[lr*40 + lk];
  short8 bA1 = *(const short8*)&btA[(16+lr)*40 + lk];
  short8 bP0 = *(const short8*)&btP[lr*40 + lk];
  short8 bP1 = *(const short8*)&btP[(16+lr)*40 + lk];
  float bias0 = pwbs[lr], bias1 = pwbs[16+lr];
  unsigned short* xrow = xb + (size_t)(b*HP + h)*ROWF;
  float* bw = buf[wid];
  const f32x4 z4 = {0.f,0.f,0.f,0.f};
  #pragma unroll
  for (int m = 0; m < 5; ++m){
    int t = wid + 4*m;
    if (t < 17){
      int w0 = t*16;
      short8 aT = *(const short8*)&Tsyn[(w0+lr)*32 + lk];
      short8 aX = *(const short8*)&xrow[(size_t)(w0+lr)*32 + lk];
      f32x4 a0 = __builtin_amdgcn_mfma_f32_16x16x32_bf16(aT, bA0, z4, 0,0,0);
      a0 = __builtin_amdgcn_mfma_f32_16x16x32_bf16(aX, bP0, a0, 0,0,0);
      f32x4 a1 = __builtin_amdgcn_mfma_f32_16x16x32_bf16(aT, bA1, z4, 0,0,0);
      a1 = __builtin_amdgcn_mfma_f32_16x16x32_bf16(aX, bP1, a1, 0,0,0);
      #pragma unroll
      for (int r = 0; r < 4; ++r){
        bw[(g*4+r)*36 + lr]      = a0[r] + bias0;
        bw[(g*4+r)*36 + 16 + lr] = a1[r] + bias1;
      }
      asm volatile("s_waitcnt lgkmcnt(0)" ::: "memory");
      __builtin_amdgcn_sched_barrier(0);
      int row = lane >> 2, c0 = (lane & 3)*8;
      int w = w0 + row;
      f32x4 v0 = *(const f32x4*)&bw[row*36 + c0];
      f32x4 v1 = *(const f32x4*)&bw[row*36 + c0 + 4];
      if (w < HP){
        unsigned short o8[8];
        #pragma unroll
        for (int q = 0; q < 4; ++q){
          float va = v0[q], vb = v1[q];
          if (l < 3){ va = gelu_f(va); vb = gelu_f(vb); }
          o8[q] = f2b(va); o8[4+q] = f2b(vb);
        }
        uint4* dst = (uint4*)&xrow[(size_t)w*32 + c0];
        *dst = make_uint4(pk(o8[0],o8[1]), pk(o8[2],o8[3]),
                          pk(o8[4],o8[5]), pk(o8[6],o8[7]));
      }
    }
  }
}

// MFMA head: fc1(32->128)+gelu -> fc2(128->3), +x_en, write pred & pred_de
__global__ __launch_bounds__(256) void k_head(const unsigned short* __restrict__ xb,
                                              const float* __restrict__ xen,
                                              const float* __restrict__ fc1w,
                                              const float* __restrict__ fc1b,
                                              const float* __restrict__ fc2w,
                                              const float* __restrict__ fc2b,
                                              float* __restrict__ out){
  __shared__ unsigned short bt1[128*40];
  __shared__ unsigned short bt2[16*136];
  __shared__ float f1bs[128];
  __shared__ float f2bs[3];
  __shared__ unsigned short Pm[4][16*136];
  __shared__ float dl[4][64*4];
  int tid = threadIdx.x;
  int b = blockIdx.x >> 8, h = blockIdx.x & 255;
  for (int i = tid; i < 4096; i += 256){
    int k = i >> 7, n = i & 127;
    bt1[n*40 + k] = f2b(fc1w[i]);
  }
  for (int i = tid; i < 2048; i += 256){
    int n = i >> 7, k = i & 127;
    bt2[n*136 + k] = (n < 3) ? f2b(fc2w[k*3 + n]) : (unsigned short)0;
  }
  if (tid < 128) f1bs[tid] = fc1b[tid];
  if (tid >= 128 && tid < 131) f2bs[tid-128] = fc2b[tid-128];
  __syncthreads();
  int wid = tid>>6, lane = tid&63, lr = lane&15, g = lane>>4, lk = g*8;
  short8 bf1[8], bf2[4];
  #pragma unroll
  for (int nt = 0; nt < 8; ++nt) bf1[nt] = *(const short8*)&bt1[(nt*16+lr)*40 + lk];
  #pragma unroll
  for (int ks = 0; ks < 4; ++ks) bf2[ks] = *(const short8*)&bt2[lr*136 + ks*32 + lk];
  const unsigned short* xrow = xb + (size_t)(b*HP + h)*ROWF;
  unsigned short* P = Pm[wid];
  float* dlw = dl[wid];
  const f32x4 z4 = {0.f,0.f,0.f,0.f};
  #pragma unroll
  for (int m = 0; m < 4; ++m){
    int p0 = (wid*4 + m)*16;
    short8 ax = *(const short8*)&xrow[(size_t)(p0 + lr)*32 + lk];
    f32x4 acc[8];
    #pragma unroll
    for (int nt = 0; nt < 8; ++nt)
      acc[nt] = __builtin_amdgcn_mfma_f32_16x16x32_bf16(ax, bf1[nt], z4, 0,0,0);
    #pragma unroll
    for (int nt = 0; nt < 8; ++nt){
      int n = nt*16 + lr;
      float bias = f1bs[n];
      #pragma unroll
      for (int r = 0; r < 4; ++r)
        P[(g*4 + r)*136 + n] = f2b(gelu_f(acc[nt][r] + bias));
    }
    asm volatile("s_waitcnt lgkmcnt(0)" ::: "memory");
    __builtin_amdgcn_sched_barrier(0);
    f32x4 a2 = z4;
    #pragma unroll
    for (int ks = 0; ks < 4; ++ks){
      short8 ap = *(const short8*)&P[lr*136 + ks*32 + lk];
      a2 = __builtin_amdgcn_mfma_f32_16x16x32_bf16(ap, bf2[ks], a2, 0,0,0);
    }
    if (lr < 3){
      #pragma unroll
      for (int r = 0; r < 4; ++r)
        dlw[(m*16 + g*4 + r)*4 + lr] = a2[r];
    }
  }
  asm volatile("s_waitcnt lgkmcnt(0)" ::: "memory");
  __builtin_amdgcn_sched_barrier(0);
  int w = wid*64 + lane;
  float d0 = dlw[lane*4+0] + f2bs[0];
  float d1 = dlw[lane*4+1] + f2bs[1];
  float d2 = dlw[lane*4+2] + f2bs[2];
  size_t be = ((size_t)b*3)*65536 + (h<<8) + w;
  float p0 = d0 + xen[be];
  float p1 = d1 + xen[be + 65536];
  float p2 = d2 + xen[be + 131072];
  out[196608 + be]          = p0;
  out[196608 + be + 65536]  = p1;
  out[196608 + be + 131072] = p2;
  if (((h|w)&3) == 0){
    size_t db = ((size_t)b*3)*4096 + ((h>>2)<<6) + (w>>2);
    out[db]        = p0;
    out[db + 4096] = p1;
    out[db + 8192] = p2;
  }
}

extern "C" void kernel_launch(void* const* d_in, const int* in_sizes, int n_in,
                              void* d_out, int out_size, void* d_ws, size_t ws_size,
                              hipStream_t stream){
  const float* x_en  = (const float*)d_in[0];
  const float* fc0_w = (const float*)d_in[2];
  const float* fc0_b = (const float*)d_in[3];
  const float* w1r   = (const float*)d_in[4];
  const float* w1i   = (const float*)d_in[5];
  const float* w2r   = (const float*)d_in[6];
  const float* w2i   = (const float*)d_in[7];
  const float* pw_w  = (const float*)d_in[8];
  const float* pw_b  = (const float*)d_in[9];
  const float* fc1_w = (const float*)d_in[10];
  const float* fc1_b = (const float*)d_in[11];
  const float* fc2_w = (const float*)d_in[12];
  const float* fc2_b = (const float*)d_in[13];
  float* out = (float*)d_out;
  float* ws  = (float*)d_ws;

  unsigned short* xb = (unsigned short*)(ws + OFF_X);
  float2* Upart = (float2*)(ws + OFF_UPART);
  float2* G     = (float2*)(ws + OFF_G);
  float*  A     = ws + OFF_A;
  float*  Tf    = ws + OFF_TF;
  unsigned short* Ts = (unsigned short*)(ws + OFF_TS);

  k_init<<<34, 256, 0, stream>>>(Tf, Ts);
  k_fc0<<<2195, 256, 0, stream>>>(x_en, fc0_w, fc0_b, xb, out);
  for (int l = 0; l < 4; ++l){
    k_dft_h<<<dim3(17,4,8), 256, 0, stream>>>(xb, Tf, Upart);
    k_spec<<<dim3(24,8), 256, 0, stream>>>(Upart, w1r, w1i, w2r, w2i, G, l);
    k_idft_h<<<256, 320, 0, stream>>>(G, A);
    k_final<<<dim3(HP,8), 256, 0, stream>>>(A, Ts, pw_w, pw_b, xb, l);
  }
  k_head<<<2048, 256, 0, stream>>>(xb, x_en, fc1_w, fc1_b, fc2_w, fc2_b, out);
}